// Round 4
// baseline (1460.283 us; speedup 1.0000x reference)
//
#include <hip/hip_runtime.h>
#include <stdint.h>

// Problem constants
#define N_ROWS 32768
#define KCODES 8192
#define DIM    512
#define DECAYF 0.8f
#define EPSF   1e-5f

// d_out layout (float32, reference return order)
#define OUT_QUANT 0
#define OUT_IND   (N_ROWS * DIM)                 // 16777216
#define OUT_CSN   (OUT_IND + N_ROWS)             // 16809984
#define OUT_AVG   (OUT_CSN + KCODES)             // 16818176
#define OUT_NORM  (OUT_AVG + KCODES * DIM)       // 21012480

// During dist_k: quant region holds Xh+Xhs (64 MiB); avg+norm regions hold Xm (32 MiB).
// All are overwritten afterwards by init2/assign/normout.
// ws: [0,256K) best u64; [256K,288K) norm2; [288K] S; [+4] inv_cs;
//     [1MiB..) Eh, Ehs, Em planes (8 MiB each). Requires ws >= 25 MiB.

typedef _Float16 f16x8 __attribute__((ext_vector_type(8)));
typedef float f32x16 __attribute__((ext_vector_type(16)));

__device__ __forceinline__ unsigned int enc_f(float v) {
    unsigned int b = __float_as_uint(v);
    return (b & 0x80000000u) ? ~b : (b | 0x80000000u);
}

__device__ __forceinline__ void gl16(const _Float16* g, const char* lds) {
    __builtin_amdgcn_global_load_lds(
        (const __attribute__((address_space(1))) unsigned int*)g,
        (__attribute__((address_space(3))) unsigned int*)lds, 16, 0, 0);
}

// ---- split fp32 -> f16 planes: h = f16(v), hs = h*2^-10 (exact), m' = f16((v-h)*1024) ----
__global__ void cvt_k(const float* __restrict__ src, _Float16* __restrict__ ph,
                      _Float16* __restrict__ phs, _Float16* __restrict__ pm, int n8) {
    int i = blockIdx.x * 256 + threadIdx.x;
    if (i >= n8) return;
    const float4* s4 = (const float4*)src;
    float4 v0 = s4[(size_t)i * 2], v1 = s4[(size_t)i * 2 + 1];
    float f[8] = {v0.x, v0.y, v0.z, v0.w, v1.x, v1.y, v1.z, v1.w};
    f16x8 hv, hsv, mv;
    const _Float16 S = (_Float16)0.0009765625f;   // 2^-10
    #pragma unroll
    for (int j = 0; j < 8; ++j) {
        _Float16 h = (_Float16)f[j];
        float r = f[j] - (float)h;
        hv[j] = h;
        hsv[j] = h * S;
        mv[j] = (_Float16)(r * 1024.0f);
    }
    *(f16x8*)(ph  + (size_t)i * 8) = hv;
    *(f16x8*)(phs + (size_t)i * 8) = hsv;
    *(f16x8*)(pm  + (size_t)i * 8) = mv;
}

__global__ void binit_k(unsigned long long* __restrict__ best) {
    int i = blockIdx.x * 256 + threadIdx.x;
    if (i < N_ROWS) best[i] = 0ull;
}

// ---- per-code squared norm (fp32 source) ----
__global__ void norms_k(const float* __restrict__ embed, float* __restrict__ norm2) {
    int gt = blockIdx.x * blockDim.x + threadIdx.x;
    int wave = gt >> 6, lane = threadIdx.x & 63;
    if (wave >= KCODES) return;
    const float4* row = (const float4*)(embed + (size_t)wave * DIM);
    float s = 0.f;
    #pragma unroll
    for (int j = 0; j < 2; ++j) {
        float4 v = row[lane * 2 + j];
        s += v.x * v.x + v.y * v.y + v.z * v.z + v.w * v.w;
    }
    #pragma unroll
    for (int off = 32; off; off >>= 1) s += __shfl_down(s, off);
    if (lane == 0) norm2[wave] = s;
}

// ---- K1: f16 3-pass (pre-scaled planes) MFMA 32x32x16 distance GEMM + fused argmax ----
#define BM 128
#define BN 128
#define BK 32
#define TILEB 8192    // bytes per plane tile: 128 rows x 32 f16

__global__ __launch_bounds__(256, 3) void dist_k(
    const _Float16* __restrict__ Xh, const _Float16* __restrict__ Xhs, const _Float16* __restrict__ Xm,
    const _Float16* __restrict__ Eh, const _Float16* __restrict__ Ehs, const _Float16* __restrict__ Em,
    const float* __restrict__ norm2, unsigned long long* __restrict__ best)
{
    __shared__ _Float16 smem[6 * 4096];   // Ah Ahs Am Bh Bhs Bm, 8 KiB each (48 KiB)
    char* sb = (char*)smem;

    const int tid = threadIdx.x;
    const int w = tid >> 6, l = tid & 63;

    // XCD column-band mapping: XCD (b&7) owns 8 consecutive bx; bx-minor, by-major.
    int b = blockIdx.x;
    int xcd = b & 7;
    int local = b >> 3;
    int bxl = local & 7;
    int by = local >> 3;
    int bx = xcd * 8 + bxl;
    const int rBase = by * BM, cBase = bx * BN;

    // staging: 2 rounds/tile/plane, linear LDS dest, pre-swizzled source (granule ^ (row>>1)&3)
    int o0 = (w << 10) | (l << 4);
    int o1 = o0 + 4096;
    int row0 = o0 >> 6, kb0 = (o0 >> 4) & 3;
    int row1 = o1 >> 6, kb1 = (o1 >> 4) & 3;
    int c0 = (kb0 ^ ((row0 >> 1) & 3)) << 3;
    int c1 = (kb1 ^ ((row1 >> 1) & 3)) << 3;
    unsigned offA0 = (unsigned)(rBase + row0) * DIM + c0;
    unsigned offA1 = (unsigned)(rBase + row1) * DIM + c1;
    unsigned offB0 = (unsigned)(cBase + row0) * DIM + c0;
    unsigned offB1 = (unsigned)(cBase + row1) * DIM + c1;
    const char* ldsw0 = sb + (w << 10);
    const char* ldsw1 = sb + 4096 + (w << 10);

    const int wr = w >> 1, wc = w & 1;     // 2x2 wave grid, 64x64 output each
    const int l31 = l & 31, l5 = l >> 5;

    // ds_read bases: lane reads row r = base + l31, granule (2*kc + l5) ^ ((r>>1)&3)
    const int rA = wr * 64 + l31;
    const int baA0 = rA * 64 + ((l5 ^ ((rA >> 1) & 3)) << 4);
    const int baA1 = baA0 ^ 32;            // kc=1: granule bit1 flip = byte bit5 flip
    const int rB = wc * 64 + l31;
    const int baB0 = rB * 64 + ((l5 ^ ((rB >> 1) & 3)) << 4);
    const int baB1 = baB0 ^ 32;

    f32x16 acc[2][2];
    #pragma unroll
    for (int i = 0; i < 2; ++i)
        #pragma unroll
        for (int j = 0; j < 2; ++j)
            #pragma unroll
            for (int r = 0; r < 16; ++r) acc[i][j][r] = 0.f;

    for (int d0 = 0; d0 < DIM; d0 += BK) {
        __syncthreads();
        gl16(Xh  + offA0 + d0, ldsw0 + 0 * TILEB);
        gl16(Xh  + offA1 + d0, ldsw1 + 0 * TILEB);
        gl16(Xhs + offA0 + d0, ldsw0 + 1 * TILEB);
        gl16(Xhs + offA1 + d0, ldsw1 + 1 * TILEB);
        gl16(Xm  + offA0 + d0, ldsw0 + 2 * TILEB);
        gl16(Xm  + offA1 + d0, ldsw1 + 2 * TILEB);
        gl16(Eh  + offB0 + d0, ldsw0 + 3 * TILEB);
        gl16(Eh  + offB1 + d0, ldsw1 + 3 * TILEB);
        gl16(Ehs + offB0 + d0, ldsw0 + 4 * TILEB);
        gl16(Ehs + offB1 + d0, ldsw1 + 4 * TILEB);
        gl16(Em  + offB0 + d0, ldsw0 + 5 * TILEB);
        gl16(Em  + offB1 + d0, ldsw1 + 5 * TILEB);
        __syncthreads();

        // passes: (h,h) (hs,m') (m',hs) -> acc accumulates hh + hm + mh
        #define PASS(AP, BP) { \
            f16x8 a00 = *(const f16x8*)(sb + AP * TILEB + baA0); \
            f16x8 a01 = *(const f16x8*)(sb + AP * TILEB + baA1); \
            f16x8 a10 = *(const f16x8*)(sb + AP * TILEB + baA0 + 2048); \
            f16x8 a11 = *(const f16x8*)(sb + AP * TILEB + baA1 + 2048); \
            f16x8 b00 = *(const f16x8*)(sb + BP * TILEB + baB0); \
            f16x8 b01 = *(const f16x8*)(sb + BP * TILEB + baB1); \
            f16x8 b10 = *(const f16x8*)(sb + BP * TILEB + baB0 + 2048); \
            f16x8 b11 = *(const f16x8*)(sb + BP * TILEB + baB1 + 2048); \
            acc[0][0] = __builtin_amdgcn_mfma_f32_32x32x16_f16(a00, b00, acc[0][0], 0, 0, 0); \
            acc[1][0] = __builtin_amdgcn_mfma_f32_32x32x16_f16(a10, b00, acc[1][0], 0, 0, 0); \
            acc[0][1] = __builtin_amdgcn_mfma_f32_32x32x16_f16(a00, b10, acc[0][1], 0, 0, 0); \
            acc[1][1] = __builtin_amdgcn_mfma_f32_32x32x16_f16(a10, b10, acc[1][1], 0, 0, 0); \
            acc[0][0] = __builtin_amdgcn_mfma_f32_32x32x16_f16(a01, b01, acc[0][0], 0, 0, 0); \
            acc[1][0] = __builtin_amdgcn_mfma_f32_32x32x16_f16(a11, b01, acc[1][0], 0, 0, 0); \
            acc[0][1] = __builtin_amdgcn_mfma_f32_32x32x16_f16(a01, b11, acc[0][1], 0, 0, 0); \
            acc[1][1] = __builtin_amdgcn_mfma_f32_32x32x16_f16(a11, b11, acc[1][1], 0, 0, 0); \
        }
        PASS(0, 3)
        PASS(1, 5)
        PASS(2, 4)
        #undef PASS
    }

    // ---- epilogue: dist = 2*dot - ||e||^2 ; argmax per x-row ----
    // C layout 32x32: col = l31 (code), row-in-tile = (reg&3) + 8*(reg>>2) + 4*l5
    float n2v0 = norm2[cBase + wc * 64 + l31];
    float n2v1 = norm2[cBase + wc * 64 + 32 + l31];
    int i0 = cBase + wc * 64 + l31;

    #pragma unroll
    for (int ai = 0; ai < 2; ++ai) {
        #pragma unroll
        for (int reg = 0; reg < 16; ++reg) {
            float v0 = 2.f * acc[ai][0][reg] - n2v0;
            float v1 = 2.f * acc[ai][1][reg] - n2v1;
            float bval = v0;
            int bidx = i0;
            if (v1 > bval) { bval = v1; bidx = i0 + 32; }   // strict > keeps smaller idx
            #pragma unroll
            for (int off = 1; off < 32; off <<= 1) {        // 5 steps within the 32-lane half
                float ov = __shfl_xor(bval, off);
                int   oi = __shfl_xor(bidx, off);
                if (ov > bval || (ov == bval && oi < bidx)) { bval = ov; bidx = oi; }
            }
            if (l31 == 0) {
                int xrow = rBase + wr * 64 + ai * 32 + (reg & 3) + 8 * (reg >> 2) + 4 * l5;
                unsigned long long key =
                    ((unsigned long long)enc_f(bval) << 32) | (unsigned int)(~(unsigned int)bidx);
                atomicMax(&best[xrow], key);
            }
        }
    }
}

// ---- post-dist init: csn = 0.8*cs ; avg = 0.8*eavg (overwrites Xm scratch) ----
__global__ void init2_k(const float* __restrict__ cs, const float* __restrict__ eavg,
                        float* __restrict__ out) {
    int i = blockIdx.x * blockDim.x + threadIdx.x;
    int stride = gridDim.x * blockDim.x;
    for (int idx = i; idx < KCODES * DIM; idx += stride) {
        out[OUT_AVG + idx] = DECAYF * eavg[idx];
        if (idx < KCODES) out[OUT_CSN + idx] = DECAYF * cs[idx];
    }
}

// ---- gather quantize + scatter counts/embed_sum ----
__global__ void assign_k(const float* __restrict__ x, const float* __restrict__ embed,
                         const unsigned long long* __restrict__ best, float* __restrict__ out) {
    int row = blockIdx.x, lane = threadIdx.x;
    int idx = (int)(~(unsigned int)best[row]);
    if (lane == 0) {
        out[OUT_IND + row] = (float)idx;
        atomicAdd(&out[OUT_CSN + idx], 0.2f);
    }
    const float4* e  = (const float4*)(embed + (size_t)idx * DIM);
    const float4* xr = (const float4*)(x + (size_t)row * DIM);
    float4* q = (float4*)(out + OUT_QUANT + (size_t)row * DIM);
    float* avg = out + OUT_AVG + (size_t)idx * DIM;
    #pragma unroll
    for (int j = lane; j < DIM / 4; j += 64) {
        q[j] = e[j];
        float4 xv = xr[j];
        atomicAdd(&avg[j * 4 + 0], 0.2f * xv.x);
        atomicAdd(&avg[j * 4 + 1], 0.2f * xv.y);
        atomicAdd(&avg[j * 4 + 2], 0.2f * xv.z);
        atomicAdd(&avg[j * 4 + 3], 0.2f * xv.w);
    }
}

__global__ void sum_k(const float* __restrict__ out, float* __restrict__ S) {
    __shared__ float red[4];
    float s = 0.f;
    for (int i = threadIdx.x; i < KCODES; i += 256) s += out[OUT_CSN + i];
    #pragma unroll
    for (int off = 32; off; off >>= 1) s += __shfl_down(s, off);
    if ((threadIdx.x & 63) == 0) red[threadIdx.x >> 6] = s;
    __syncthreads();
    if (threadIdx.x == 0) S[0] = red[0] + red[1] + red[2] + red[3];
}

__global__ void inv_k(const float* __restrict__ out, const float* __restrict__ S,
                      float* __restrict__ inv_cs) {
    int k = blockIdx.x * 256 + threadIdx.x;
    if (k >= KCODES) return;
    float Sv = S[0];
    inv_cs[k] = (Sv + (float)KCODES * EPSF) / ((out[OUT_CSN + k] + EPSF) * Sv);
}

__global__ void normout_k(float* __restrict__ out, const float* __restrict__ inv_cs) {
    int i = blockIdx.x * 256 + threadIdx.x;
    const float4* avg = (const float4*)(out + OUT_AVG);
    float4* nrm = (float4*)(out + OUT_NORM);
    float inv = inv_cs[i >> 7];
    float4 v = avg[i];
    v.x *= inv; v.y *= inv; v.z *= inv; v.w *= inv;
    nrm[i] = v;
}

extern "C" void kernel_launch(void* const* d_in, const int* in_sizes, int n_in,
                              void* d_out, int out_size, void* d_ws, size_t ws_size,
                              hipStream_t stream) {
    const float* x     = (const float*)d_in[0];
    const float* embed = (const float*)d_in[1];
    const float* cs    = (const float*)d_in[2];
    const float* eavg  = (const float*)d_in[3];
    float* out = (float*)d_out;
    char*  w   = (char*)d_ws;

    unsigned long long* best = (unsigned long long*)w;
    float* norm2  = (float*)(w + 262144);
    float* Ssum   = (float*)(w + 294912);
    float* inv_cs = Ssum + 1;
    _Float16* Eh  = (_Float16*)(w + (1u << 20));
    _Float16* Ehs = Eh  + (size_t)KCODES * DIM;
    _Float16* Em  = Ehs + (size_t)KCODES * DIM;

    // X planes: quant region holds Xh+Xhs (exactly 64 MiB); avg+norm hold Xm (exactly 32 MiB)
    _Float16* Xh  = (_Float16*)out;
    _Float16* Xhs = Xh + (size_t)N_ROWS * DIM;
    _Float16* Xm  = (_Float16*)(out + OUT_AVG);

    binit_k<<<N_ROWS / 256, 256, 0, stream>>>(best);
    cvt_k<<<(N_ROWS * DIM / 8) / 256, 256, 0, stream>>>(x, Xh, Xhs, Xm, N_ROWS * DIM / 8);
    cvt_k<<<(KCODES * DIM / 8) / 256, 256, 0, stream>>>(embed, Eh, Ehs, Em, KCODES * DIM / 8);
    norms_k<<<(KCODES * 64) / 256, 256, 0, stream>>>(embed, norm2);
    dist_k<<<(N_ROWS / BM) * (KCODES / BN), 256, 0, stream>>>(Xh, Xhs, Xm, Eh, Ehs, Em, norm2, best);
    init2_k<<<2048, 256, 0, stream>>>(cs, eavg, out);
    assign_k<<<N_ROWS, 64, 0, stream>>>(x, embed, best, out);
    sum_k<<<1, 256, 0, stream>>>(out, Ssum);
    inv_k<<<KCODES / 256, 256, 0, stream>>>(out, Ssum, inv_cs);
    normout_k<<<(KCODES * DIM / 4) / 256, 256, 0, stream>>>(out, inv_cs);
}

// Round 5
// 1133.097 us; speedup vs baseline: 1.2888x; 1.2888x over previous
//
#include <hip/hip_runtime.h>
#include <stdint.h>

// Problem constants
#define N_ROWS 32768
#define KCODES 8192
#define DIM    512
#define DECAYF 0.8f
#define EPSF   1e-5f

// d_out layout (float32, reference return order)
#define OUT_QUANT 0
#define OUT_IND   (N_ROWS * DIM)                 // 16777216
#define OUT_CSN   (OUT_IND + N_ROWS)             // 16809984
#define OUT_AVG   (OUT_CSN + KCODES)             // 16818176
#define OUT_NORM  (OUT_AVG + KCODES * DIM)       // 21012480

// During dist_k the quant region (64 MiB) holds the X f16 planes (Xh 32 MiB + Xm 32 MiB);
// overwritten by assign_k afterwards.
// ws: [0,256K) best u64; [256K,288K) norm2; [288K] S; [+4] inv_cs; [1MiB..) Eh, Em (8 MiB each).

typedef _Float16 f16x8 __attribute__((ext_vector_type(8)));
typedef __attribute__((ext_vector_type(4))) float f32x4;

__device__ __forceinline__ unsigned int enc_f(float v) {
    unsigned int b = __float_as_uint(v);
    return (b & 0x80000000u) ? ~b : (b | 0x80000000u);
}

__device__ __forceinline__ void gl16(const _Float16* g, const char* lds) {
    __builtin_amdgcn_global_load_lds(
        (const __attribute__((address_space(1))) unsigned int*)g,
        (__attribute__((address_space(3))) unsigned int*)lds, 16, 0, 0);
}

// ---- split fp32 -> f16 planes: h = f16(v), m' = f16((v-h)*1024) ----
__global__ void cvt_k(const float* __restrict__ src, _Float16* __restrict__ ph,
                      _Float16* __restrict__ pm, int n8) {
    int i = blockIdx.x * 256 + threadIdx.x;
    if (i >= n8) return;
    const float4* s4 = (const float4*)src;
    float4 v0 = s4[(size_t)i * 2], v1 = s4[(size_t)i * 2 + 1];
    float f[8] = {v0.x, v0.y, v0.z, v0.w, v1.x, v1.y, v1.z, v1.w};
    f16x8 hv, mv;
    #pragma unroll
    for (int j = 0; j < 8; ++j) {
        _Float16 h = (_Float16)f[j];
        float r = f[j] - (float)h;
        hv[j] = h;
        mv[j] = (_Float16)(r * 1024.0f);
    }
    *(f16x8*)(ph + (size_t)i * 8) = hv;
    *(f16x8*)(pm + (size_t)i * 8) = mv;
}

__global__ void binit_k(unsigned long long* __restrict__ best) {
    int i = blockIdx.x * 256 + threadIdx.x;
    if (i < N_ROWS) best[i] = 0ull;
}

// ---- per-code squared norm (fp32 source) ----
__global__ void norms_k(const float* __restrict__ embed, float* __restrict__ norm2) {
    int gt = blockIdx.x * blockDim.x + threadIdx.x;
    int wave = gt >> 6, lane = threadIdx.x & 63;
    if (wave >= KCODES) return;
    const float4* row = (const float4*)(embed + (size_t)wave * DIM);
    float s = 0.f;
    #pragma unroll
    for (int j = 0; j < 2; ++j) {
        float4 v = row[lane * 2 + j];
        s += v.x * v.x + v.y * v.y + v.z * v.z + v.w * v.w;
    }
    #pragma unroll
    for (int off = 32; off; off >>= 1) s += __shfl_down(s, off);
    if (lane == 0) norm2[wave] = s;
}

// ---- K1: f16 3-pass dual-accumulator MFMA GEMM, 2-phase prefetch pipeline ----
#define BM 128
#define BN 128
#define BK 32
#define TILEB 8192      // bytes per plane tile: 128 rows x 32 f16
#define LBUF  32768     // one LDS buffer: 4 planes (Ah Am Bh Bm)

__global__ __launch_bounds__(256, 2) void dist_k(
    const _Float16* __restrict__ Xh, const _Float16* __restrict__ Xm,
    const _Float16* __restrict__ Eh, const _Float16* __restrict__ Em,
    const float* __restrict__ norm2, unsigned long long* __restrict__ best)
{
    __shared__ _Float16 smem[2 * 4 * 4096];   // 64 KiB: 2 x (Ah Am Bh Bm)
    char* sb = (char*)smem;

    const int tid = threadIdx.x;
    const int w = tid >> 6, l = tid & 63;

    // XCD column-band mapping: XCD (b&7) owns 8 consecutive bx; bx-minor, by-major.
    int b = blockIdx.x;
    int xcd = b & 7;
    int local = b >> 3;
    int bxl = local & 7;
    int by = local >> 3;
    int bx = xcd * 8 + bxl;
    const int rBase = by * BM, cBase = bx * BN;

    // staging: 2 rounds/plane, linear LDS dest, pre-swizzled source (granule ^ (row>>1)&3)
    int o0 = (w << 10) | (l << 4);
    int o1 = o0 + 4096;
    int row0 = o0 >> 6, kb0 = (o0 >> 4) & 3;
    int row1 = o1 >> 6, kb1 = (o1 >> 4) & 3;
    int c0 = (kb0 ^ ((row0 >> 1) & 3)) << 3;
    int c1 = (kb1 ^ ((row1 >> 1) & 3)) << 3;
    unsigned offA0 = (unsigned)(rBase + row0) * DIM + c0;
    unsigned offA1 = (unsigned)(rBase + row1) * DIM + c1;
    unsigned offB0 = (unsigned)(cBase + row0) * DIM + c0;
    unsigned offB1 = (unsigned)(cBase + row1) * DIM + c1;
    const int w1024 = w << 10;

    const int wr = w >> 1, wc = w & 1;     // 2x2 wave grid, 64x64 output each
    const int ln = l & 15, kq = l >> 4;

    // ds_read bases (proven conflict-free 16x16 geometry from R3)
    const int rA = wr * 64 + ln;
    const int baA = rA * 64 + ((kq ^ ((rA >> 1) & 3)) << 4);
    const int rB = wc * 64 + ln;
    const int baB = rB * 64 + ((kq ^ ((rB >> 1) & 3)) << 4);

    f32x4 acc1[4][4], acc2[4][4];
    #pragma unroll
    for (int i = 0; i < 4; ++i)
        #pragma unroll
        for (int j = 0; j < 4; ++j) {
            acc1[i][j] = (f32x4){0.f, 0.f, 0.f, 0.f};
            acc2[i][j] = (f32x4){0.f, 0.f, 0.f, 0.f};
        }

    // stage 4 planes (8 gl16) for K-chunk at element offset D0 into buffer at byte BUFOFF
    #define STAGE(BUFOFF, D0) { \
        gl16(Xh + offA0 + (D0), sb + (BUFOFF) + 0 * TILEB + w1024); \
        gl16(Xh + offA1 + (D0), sb + (BUFOFF) + 0 * TILEB + 4096 + w1024); \
        gl16(Xm + offA0 + (D0), sb + (BUFOFF) + 1 * TILEB + w1024); \
        gl16(Xm + offA1 + (D0), sb + (BUFOFF) + 1 * TILEB + 4096 + w1024); \
        gl16(Eh + offB0 + (D0), sb + (BUFOFF) + 2 * TILEB + w1024); \
        gl16(Eh + offB1 + (D0), sb + (BUFOFF) + 2 * TILEB + 4096 + w1024); \
        gl16(Em + offB0 + (D0), sb + (BUFOFF) + 3 * TILEB + w1024); \
        gl16(Em + offB1 + (D0), sb + (BUFOFF) + 3 * TILEB + 4096 + w1024); \
    }

    // compute on buffer at byte BUFOFF: read 16 frags, 48 MFMA (3 passes)
    #define COMPUTE(BUFOFF) { \
        f16x8 ah[4], am[4], bh[4], bm[4]; \
        _Pragma("unroll") \
        for (int ai = 0; ai < 4; ++ai) { \
            ah[ai] = *(const f16x8*)(sb + (BUFOFF) + 0 * TILEB + baA + ai * 1024); \
            am[ai] = *(const f16x8*)(sb + (BUFOFF) + 1 * TILEB + baA + ai * 1024); \
        } \
        _Pragma("unroll") \
        for (int bj = 0; bj < 4; ++bj) { \
            bh[bj] = *(const f16x8*)(sb + (BUFOFF) + 2 * TILEB + baB + bj * 1024); \
            bm[bj] = *(const f16x8*)(sb + (BUFOFF) + 3 * TILEB + baB + bj * 1024); \
        } \
        _Pragma("unroll") \
        for (int bj = 0; bj < 4; ++bj) \
            _Pragma("unroll") \
            for (int ai = 0; ai < 4; ++ai) \
                acc1[ai][bj] = __builtin_amdgcn_mfma_f32_16x16x32_f16(ah[ai], bh[bj], acc1[ai][bj], 0, 0, 0); \
        _Pragma("unroll") \
        for (int bj = 0; bj < 4; ++bj) \
            _Pragma("unroll") \
            for (int ai = 0; ai < 4; ++ai) \
                acc2[ai][bj] = __builtin_amdgcn_mfma_f32_16x16x32_f16(ah[ai], bm[bj], acc2[ai][bj], 0, 0, 0); \
        _Pragma("unroll") \
        for (int bj = 0; bj < 4; ++bj) \
            _Pragma("unroll") \
            for (int ai = 0; ai < 4; ++ai) \
                acc2[ai][bj] = __builtin_amdgcn_mfma_f32_16x16x32_f16(am[ai], bh[bj], acc2[ai][bj], 0, 0, 0); \
    }

    // prologue: fill buf0 with K-chunk 0
    STAGE(0, 0)
    __syncthreads();

    // 16 K-steps, unrolled in pairs: even -> read buf0/stage buf1, odd -> read buf1/stage buf0
    #pragma unroll
    for (int it = 0; it < 8; ++it) {
        int d0 = it * 64;
        STAGE(LBUF, d0 + 32)          // t = 2*it stages t+1 (always valid: t <= 14)
        COMPUTE(0)
        __syncthreads();              // drain stage loads + protect buf1
        if (it < 7) STAGE(0, d0 + 64) // t = 2*it+1 stages t+1
        COMPUTE(LBUF)
        __syncthreads();
    }
    #undef STAGE
    #undef COMPUTE

    // ---- epilogue: dot = acc1 + 2^-10 * acc2 ; dist = 2*dot - ||e||^2 ; argmax ----
    const float S = 0.0009765625f;   // 2^-10
    float n2v[4];
    #pragma unroll
    for (int bj = 0; bj < 4; ++bj)
        n2v[bj] = norm2[cBase + wc * 64 + bj * 16 + ln];

    #pragma unroll
    for (int ai = 0; ai < 4; ++ai) {
        #pragma unroll
        for (int r = 0; r < 4; ++r) {
            float bval = -3.4e38f;
            int bidx = 0;
            #pragma unroll
            for (int bj = 0; bj < 4; ++bj) {
                float v = 2.f * (acc1[ai][bj][r] + S * acc2[ai][bj][r]) - n2v[bj];
                if (v > bval) { bval = v; bidx = cBase + wc * 64 + bj * 16 + ln; }
            }
            #pragma unroll
            for (int off = 1; off < 16; off <<= 1) {
                float ov = __shfl_xor(bval, off);
                int   oi = __shfl_xor(bidx, off);
                if (ov > bval || (ov == bval && oi < bidx)) { bval = ov; bidx = oi; }
            }
            if (ln == 0) {
                unsigned long long key =
                    ((unsigned long long)enc_f(bval) << 32) | (unsigned int)(~(unsigned int)bidx);
                atomicMax(&best[rBase + wr * 64 + ai * 16 + kq * 4 + r], key);
            }
        }
    }
}

// ---- post-dist init: csn = 0.8*cs ; avg = 0.8*eavg ----
__global__ void init2_k(const float* __restrict__ cs, const float* __restrict__ eavg,
                        float* __restrict__ out) {
    int i = blockIdx.x * blockDim.x + threadIdx.x;
    int stride = gridDim.x * blockDim.x;
    for (int idx = i; idx < KCODES * DIM; idx += stride) {
        out[OUT_AVG + idx] = DECAYF * eavg[idx];
        if (idx < KCODES) out[OUT_CSN + idx] = DECAYF * cs[idx];
    }
}

// ---- gather quantize + scatter counts/embed_sum ----
__global__ void assign_k(const float* __restrict__ x, const float* __restrict__ embed,
                         const unsigned long long* __restrict__ best, float* __restrict__ out) {
    int row = blockIdx.x, lane = threadIdx.x;
    int idx = (int)(~(unsigned int)best[row]);
    if (lane == 0) {
        out[OUT_IND + row] = (float)idx;
        atomicAdd(&out[OUT_CSN + idx], 0.2f);
    }
    const float4* e  = (const float4*)(embed + (size_t)idx * DIM);
    const float4* xr = (const float4*)(x + (size_t)row * DIM);
    float4* q = (float4*)(out + OUT_QUANT + (size_t)row * DIM);
    float* avg = out + OUT_AVG + (size_t)idx * DIM;
    #pragma unroll
    for (int j = lane; j < DIM / 4; j += 64) {
        q[j] = e[j];
        float4 xv = xr[j];
        atomicAdd(&avg[j * 4 + 0], 0.2f * xv.x);
        atomicAdd(&avg[j * 4 + 1], 0.2f * xv.y);
        atomicAdd(&avg[j * 4 + 2], 0.2f * xv.z);
        atomicAdd(&avg[j * 4 + 3], 0.2f * xv.w);
    }
}

__global__ void sum_k(const float* __restrict__ out, float* __restrict__ S) {
    __shared__ float red[4];
    float s = 0.f;
    for (int i = threadIdx.x; i < KCODES; i += 256) s += out[OUT_CSN + i];
    #pragma unroll
    for (int off = 32; off; off >>= 1) s += __shfl_down(s, off);
    if ((threadIdx.x & 63) == 0) red[threadIdx.x >> 6] = s;
    __syncthreads();
    if (threadIdx.x == 0) S[0] = red[0] + red[1] + red[2] + red[3];
}

__global__ void inv_k(const float* __restrict__ out, const float* __restrict__ S,
                      float* __restrict__ inv_cs) {
    int k = blockIdx.x * 256 + threadIdx.x;
    if (k >= KCODES) return;
    float Sv = S[0];
    inv_cs[k] = (Sv + (float)KCODES * EPSF) / ((out[OUT_CSN + k] + EPSF) * Sv);
}

__global__ void normout_k(float* __restrict__ out, const float* __restrict__ inv_cs) {
    int i = blockIdx.x * 256 + threadIdx.x;
    const float4* avg = (const float4*)(out + OUT_AVG);
    float4* nrm = (float4*)(out + OUT_NORM);
    float inv = inv_cs[i >> 7];
    float4 v = avg[i];
    v.x *= inv; v.y *= inv; v.z *= inv; v.w *= inv;
    nrm[i] = v;
}

extern "C" void kernel_launch(void* const* d_in, const int* in_sizes, int n_in,
                              void* d_out, int out_size, void* d_ws, size_t ws_size,
                              hipStream_t stream) {
    const float* x     = (const float*)d_in[0];
    const float* embed = (const float*)d_in[1];
    const float* cs    = (const float*)d_in[2];
    const float* eavg  = (const float*)d_in[3];
    float* out = (float*)d_out;
    char*  w   = (char*)d_ws;

    unsigned long long* best = (unsigned long long*)w;
    float* norm2  = (float*)(w + 262144);
    float* Ssum   = (float*)(w + 294912);
    float* inv_cs = Ssum + 1;
    _Float16* Eh = (_Float16*)(w + (1u << 20));
    _Float16* Em = Eh + (size_t)KCODES * DIM;

    // X planes exactly fill the quant region (64 MiB), rewritten later by assign_k
    _Float16* Xh = (_Float16*)out;
    _Float16* Xm = Xh + (size_t)N_ROWS * DIM;

    binit_k<<<N_ROWS / 256, 256, 0, stream>>>(best);
    cvt_k<<<(N_ROWS * DIM / 8) / 256, 256, 0, stream>>>(x, Xh, Xm, N_ROWS * DIM / 8);
    cvt_k<<<(KCODES * DIM / 8) / 256, 256, 0, stream>>>(embed, Eh, Em, KCODES * DIM / 8);
    norms_k<<<(KCODES * 64) / 256, 256, 0, stream>>>(embed, norm2);
    dist_k<<<(N_ROWS / BM) * (KCODES / BN), 256, 0, stream>>>(Xh, Xm, Eh, Em, norm2, best);
    init2_k<<<2048, 256, 0, stream>>>(cs, eavg, out);
    assign_k<<<N_ROWS, 64, 0, stream>>>(x, embed, best, out);
    sum_k<<<1, 256, 0, stream>>>(out, Ssum);
    inv_k<<<KCODES / 256, 256, 0, stream>>>(out, Ssum, inv_cs);
    normout_k<<<(KCODES * DIM / 4) / 256, 256, 0, stream>>>(out, inv_cs);
}

// Round 6
// 1085.054 us; speedup vs baseline: 1.3458x; 1.0443x over previous
//
#include <hip/hip_runtime.h>
#include <stdint.h>

// Problem constants
#define N_ROWS 32768
#define KCODES 8192
#define DIM    512
#define DECAYF 0.8f
#define EPSF   1e-5f

// d_out layout (float32, reference return order)
#define OUT_QUANT 0
#define OUT_IND   (N_ROWS * DIM)                 // 16777216
#define OUT_CSN   (OUT_IND + N_ROWS)             // 16809984
#define OUT_AVG   (OUT_CSN + KCODES)             // 16818176
#define OUT_NORM  (OUT_AVG + KCODES * DIM)       // 21012480

// During dist_k the quant region (64 MiB) holds the X f16 planes (Xh 32 MiB + Xm 32 MiB);
// overwritten by assign_k afterwards.
// ws: [0,256K) best u64; [256K,288K) norm2; [288K] S; [+4] inv_cs; [1MiB..) Eh, Em (8 MiB each).

typedef _Float16 f16x8 __attribute__((ext_vector_type(8)));
typedef __attribute__((ext_vector_type(4))) float f32x4;

__device__ __forceinline__ unsigned int enc_f(float v) {
    unsigned int b = __float_as_uint(v);
    return (b & 0x80000000u) ? ~b : (b | 0x80000000u);
}

__device__ __forceinline__ void gl16(const _Float16* g, const char* lds) {
    __builtin_amdgcn_global_load_lds(
        (const __attribute__((address_space(1))) unsigned int*)g,
        (__attribute__((address_space(3))) unsigned int*)lds, 16, 0, 0);
}

// ---- split fp32 -> f16 planes: h = f16(v), m' = f16((v-h)*1024) ----
__global__ void cvt_k(const float* __restrict__ src, _Float16* __restrict__ ph,
                      _Float16* __restrict__ pm, int n8) {
    int i = blockIdx.x * 256 + threadIdx.x;
    if (i >= n8) return;
    const float4* s4 = (const float4*)src;
    float4 v0 = s4[(size_t)i * 2], v1 = s4[(size_t)i * 2 + 1];
    float f[8] = {v0.x, v0.y, v0.z, v0.w, v1.x, v1.y, v1.z, v1.w};
    f16x8 hv, mv;
    #pragma unroll
    for (int j = 0; j < 8; ++j) {
        _Float16 h = (_Float16)f[j];
        float r = f[j] - (float)h;
        hv[j] = h;
        mv[j] = (_Float16)(r * 1024.0f);
    }
    *(f16x8*)(ph + (size_t)i * 8) = hv;
    *(f16x8*)(pm + (size_t)i * 8) = mv;
}

__global__ void binit_k(unsigned long long* __restrict__ best) {
    int i = blockIdx.x * 256 + threadIdx.x;
    if (i < N_ROWS) best[i] = 0ull;
}

// ---- per-code squared norm (fp32 source) ----
__global__ void norms_k(const float* __restrict__ embed, float* __restrict__ norm2) {
    int gt = blockIdx.x * blockDim.x + threadIdx.x;
    int wave = gt >> 6, lane = threadIdx.x & 63;
    if (wave >= KCODES) return;
    const float4* row = (const float4*)(embed + (size_t)wave * DIM);
    float s = 0.f;
    #pragma unroll
    for (int j = 0; j < 2; ++j) {
        float4 v = row[lane * 2 + j];
        s += v.x * v.x + v.y * v.y + v.z * v.z + v.w * v.w;
    }
    #pragma unroll
    for (int off = 32; off; off >>= 1) s += __shfl_down(s, off);
    if (lane == 0) norm2[wave] = s;
}

// ---- K1: f16 3-pass dual-accumulator MFMA GEMM, counted-vmcnt 2-buffer pipeline ----
#define BM 128
#define BN 128
#define BK 32
#define TILEB 8192      // bytes per plane tile: 128 rows x 32 f16
#define LBUF  32768     // one LDS buffer: 4 planes (Ah Am Bh Bm)

__global__ __launch_bounds__(256, 2) void dist_k(
    const _Float16* __restrict__ Xh, const _Float16* __restrict__ Xm,
    const _Float16* __restrict__ Eh, const _Float16* __restrict__ Em,
    const float* __restrict__ norm2, unsigned long long* __restrict__ best)
{
    __shared__ _Float16 smem[2 * 4 * 4096];   // 64 KiB: 2 x (Ah Am Bh Bm)
    char* sb = (char*)smem;

    const int tid = threadIdx.x;
    const int w = tid >> 6, l = tid & 63;

    // XCD column-band mapping: XCD (b&7) owns 8 consecutive bx; bx-minor, by-major.
    int b = blockIdx.x;
    int xcd = b & 7;
    int local = b >> 3;
    int bxl = local & 7;
    int by = local >> 3;
    int bx = xcd * 8 + bxl;
    const int rBase = by * BM, cBase = bx * BN;

    // staging: 2 rounds/plane, linear LDS dest, pre-swizzled source (granule ^ (row>>1)&3)
    int o0 = (w << 10) | (l << 4);
    int o1 = o0 + 4096;
    int row0 = o0 >> 6, kb0 = (o0 >> 4) & 3;
    int row1 = o1 >> 6, kb1 = (o1 >> 4) & 3;
    int c0 = (kb0 ^ ((row0 >> 1) & 3)) << 3;
    int c1 = (kb1 ^ ((row1 >> 1) & 3)) << 3;
    unsigned offA0 = (unsigned)(rBase + row0) * DIM + c0;
    unsigned offA1 = (unsigned)(rBase + row1) * DIM + c1;
    unsigned offB0 = (unsigned)(cBase + row0) * DIM + c0;
    unsigned offB1 = (unsigned)(cBase + row1) * DIM + c1;
    const int w1024 = w << 10;

    const int wr = w >> 1, wc = w & 1;     // 2x2 wave grid, 64x64 output each
    const int ln = l & 15, kq = l >> 4;

    // ds_read bases (proven conflict-free 16x16 geometry from R3)
    const int rA = wr * 64 + ln;
    const int baA = rA * 64 + ((kq ^ ((rA >> 1) & 3)) << 4);
    const int rB = wc * 64 + ln;
    const int baB = rB * 64 + ((kq ^ ((rB >> 1) & 3)) << 4);

    f32x4 acc1[4][4], acc2[4][4];
    #pragma unroll
    for (int i = 0; i < 4; ++i)
        #pragma unroll
        for (int j = 0; j < 4; ++j) {
            acc1[i][j] = (f32x4){0.f, 0.f, 0.f, 0.f};
            acc2[i][j] = (f32x4){0.f, 0.f, 0.f, 0.f};
        }

    // stage 4 planes (8 gl16) for K-chunk at element offset D0 into buffer at byte BUFOFF
    #define STAGE(BUFOFF, D0) { \
        gl16(Xh + offA0 + (D0), sb + (BUFOFF) + 0 * TILEB + w1024); \
        gl16(Xh + offA1 + (D0), sb + (BUFOFF) + 0 * TILEB + 4096 + w1024); \
        gl16(Xm + offA0 + (D0), sb + (BUFOFF) + 1 * TILEB + w1024); \
        gl16(Xm + offA1 + (D0), sb + (BUFOFF) + 1 * TILEB + 4096 + w1024); \
        gl16(Eh + offB0 + (D0), sb + (BUFOFF) + 2 * TILEB + w1024); \
        gl16(Eh + offB1 + (D0), sb + (BUFOFF) + 2 * TILEB + 4096 + w1024); \
        gl16(Em + offB0 + (D0), sb + (BUFOFF) + 3 * TILEB + w1024); \
        gl16(Em + offB1 + (D0), sb + (BUFOFF) + 3 * TILEB + 4096 + w1024); \
    }

    // compute on buffer at byte BUFOFF: read 16 frags, 48 MFMA (3 passes)
    #define COMPUTE(BUFOFF) { \
        f16x8 ah[4], am[4], bh[4], bm[4]; \
        _Pragma("unroll") \
        for (int ai = 0; ai < 4; ++ai) { \
            ah[ai] = *(const f16x8*)(sb + (BUFOFF) + 0 * TILEB + baA + ai * 1024); \
            am[ai] = *(const f16x8*)(sb + (BUFOFF) + 1 * TILEB + baA + ai * 1024); \
        } \
        _Pragma("unroll") \
        for (int bj = 0; bj < 4; ++bj) { \
            bh[bj] = *(const f16x8*)(sb + (BUFOFF) + 2 * TILEB + baB + bj * 1024); \
            bm[bj] = *(const f16x8*)(sb + (BUFOFF) + 3 * TILEB + baB + bj * 1024); \
        } \
        _Pragma("unroll") \
        for (int bj = 0; bj < 4; ++bj) \
            _Pragma("unroll") \
            for (int ai = 0; ai < 4; ++ai) \
                acc1[ai][bj] = __builtin_amdgcn_mfma_f32_16x16x32_f16(ah[ai], bh[bj], acc1[ai][bj], 0, 0, 0); \
        _Pragma("unroll") \
        for (int bj = 0; bj < 4; ++bj) \
            _Pragma("unroll") \
            for (int ai = 0; ai < 4; ++ai) \
                acc2[ai][bj] = __builtin_amdgcn_mfma_f32_16x16x32_f16(ah[ai], bm[bj], acc2[ai][bj], 0, 0, 0); \
        _Pragma("unroll") \
        for (int bj = 0; bj < 4; ++bj) \
            _Pragma("unroll") \
            for (int ai = 0; ai < 4; ++ai) \
                acc2[ai][bj] = __builtin_amdgcn_mfma_f32_16x16x32_f16(am[ai], bh[bj], acc2[ai][bj], 0, 0, 0); \
    }

    // T4 counted-vmcnt pipeline: never drain in-flight prefetch.
    // Before consuming a buffer: 8 own loads must be done, 8 next-buffer loads stay
    // in flight -> s_waitcnt vmcnt(8) + raw s_barrier (each wave's stores complete
    // before its barrier => all staging visible after barrier). Post-compute barrier
    // needs no waitcnt: every ds_read is consumed by an in-COMPUTE MFMA (compiler
    // lgkmcnt), so reads are complete before the wave reaches the barrier.
    STAGE(0, 0)
    #pragma unroll
    for (int it = 0; it < 8; ++it) {
        int d0 = it * 64;
        // even step t=2it: stage chunk t+1 into buf1, compute chunk t from buf0
        STAGE(LBUF, d0 + 32)
        asm volatile("s_waitcnt vmcnt(8)" ::: "memory");
        __builtin_amdgcn_s_barrier();
        __builtin_amdgcn_sched_barrier(0);
        COMPUTE(0)
        __builtin_amdgcn_s_barrier();
        // odd step t=2it+1: stage chunk t+1 into buf0 (if any), compute from buf1
        if (it < 7) {
            STAGE(0, d0 + 64)
            asm volatile("s_waitcnt vmcnt(8)" ::: "memory");
        } else {
            asm volatile("s_waitcnt vmcnt(0)" ::: "memory");
        }
        __builtin_amdgcn_s_barrier();
        __builtin_amdgcn_sched_barrier(0);
        COMPUTE(LBUF)
        __builtin_amdgcn_s_barrier();
    }
    #undef STAGE
    #undef COMPUTE

    // ---- epilogue: dot = acc1 + 2^-10 * acc2 ; dist = 2*dot - ||e||^2 ; argmax ----
    const float S = 0.0009765625f;   // 2^-10
    float n2v[4];
    #pragma unroll
    for (int bj = 0; bj < 4; ++bj)
        n2v[bj] = norm2[cBase + wc * 64 + bj * 16 + ln];

    #pragma unroll
    for (int ai = 0; ai < 4; ++ai) {
        #pragma unroll
        for (int r = 0; r < 4; ++r) {
            float bval = -3.4e38f;
            int bidx = 0;
            #pragma unroll
            for (int bj = 0; bj < 4; ++bj) {
                float v = 2.f * (acc1[ai][bj][r] + S * acc2[ai][bj][r]) - n2v[bj];
                if (v > bval) { bval = v; bidx = cBase + wc * 64 + bj * 16 + ln; }
            }
            #pragma unroll
            for (int off = 1; off < 16; off <<= 1) {
                float ov = __shfl_xor(bval, off);
                int   oi = __shfl_xor(bidx, off);
                if (ov > bval || (ov == bval && oi < bidx)) { bval = ov; bidx = oi; }
            }
            if (ln == 0) {
                unsigned long long key =
                    ((unsigned long long)enc_f(bval) << 32) | (unsigned int)(~(unsigned int)bidx);
                atomicMax(&best[rBase + wr * 64 + ai * 16 + kq * 4 + r], key);
            }
        }
    }
}

// ---- post-dist init: csn = 0.8*cs ; avg = 0.8*eavg ----
__global__ void init2_k(const float* __restrict__ cs, const float* __restrict__ eavg,
                        float* __restrict__ out) {
    int i = blockIdx.x * blockDim.x + threadIdx.x;
    int stride = gridDim.x * blockDim.x;
    for (int idx = i; idx < KCODES * DIM; idx += stride) {
        out[OUT_AVG + idx] = DECAYF * eavg[idx];
        if (idx < KCODES) out[OUT_CSN + idx] = DECAYF * cs[idx];
    }
}

// ---- gather quantize + scatter counts/embed_sum ----
__global__ void assign_k(const float* __restrict__ x, const float* __restrict__ embed,
                         const unsigned long long* __restrict__ best, float* __restrict__ out) {
    int row = blockIdx.x, lane = threadIdx.x;
    int idx = (int)(~(unsigned int)best[row]);
    if (lane == 0) {
        out[OUT_IND + row] = (float)idx;
        atomicAdd(&out[OUT_CSN + idx], 0.2f);
    }
    const float4* e  = (const float4*)(embed + (size_t)idx * DIM);
    const float4* xr = (const float4*)(x + (size_t)row * DIM);
    float4* q = (float4*)(out + OUT_QUANT + (size_t)row * DIM);
    float* avg = out + OUT_AVG + (size_t)idx * DIM;
    #pragma unroll
    for (int j = lane; j < DIM / 4; j += 64) {
        q[j] = e[j];
        float4 xv = xr[j];
        atomicAdd(&avg[j * 4 + 0], 0.2f * xv.x);
        atomicAdd(&avg[j * 4 + 1], 0.2f * xv.y);
        atomicAdd(&avg[j * 4 + 2], 0.2f * xv.z);
        atomicAdd(&avg[j * 4 + 3], 0.2f * xv.w);
    }
}

__global__ void sum_k(const float* __restrict__ out, float* __restrict__ S) {
    __shared__ float red[4];
    float s = 0.f;
    for (int i = threadIdx.x; i < KCODES; i += 256) s += out[OUT_CSN + i];
    #pragma unroll
    for (int off = 32; off; off >>= 1) s += __shfl_down(s, off);
    if ((threadIdx.x & 63) == 0) red[threadIdx.x >> 6] = s;
    __syncthreads();
    if (threadIdx.x == 0) S[0] = red[0] + red[1] + red[2] + red[3];
}

__global__ void inv_k(const float* __restrict__ out, const float* __restrict__ S,
                      float* __restrict__ inv_cs) {
    int k = blockIdx.x * 256 + threadIdx.x;
    if (k >= KCODES) return;
    float Sv = S[0];
    inv_cs[k] = (Sv + (float)KCODES * EPSF) / ((out[OUT_CSN + k] + EPSF) * Sv);
}

__global__ void normout_k(float* __restrict__ out, const float* __restrict__ inv_cs) {
    int i = blockIdx.x * 256 + threadIdx.x;
    const float4* avg = (const float4*)(out + OUT_AVG);
    float4* nrm = (float4*)(out + OUT_NORM);
    float inv = inv_cs[i >> 7];
    float4 v = avg[i];
    v.x *= inv; v.y *= inv; v.z *= inv; v.w *= inv;
    nrm[i] = v;
}

extern "C" void kernel_launch(void* const* d_in, const int* in_sizes, int n_in,
                              void* d_out, int out_size, void* d_ws, size_t ws_size,
                              hipStream_t stream) {
    const float* x     = (const float*)d_in[0];
    const float* embed = (const float*)d_in[1];
    const float* cs    = (const float*)d_in[2];
    const float* eavg  = (const float*)d_in[3];
    float* out = (float*)d_out;
    char*  w   = (char*)d_ws;

    unsigned long long* best = (unsigned long long*)w;
    float* norm2  = (float*)(w + 262144);
    float* Ssum   = (float*)(w + 294912);
    float* inv_cs = Ssum + 1;
    _Float16* Eh = (_Float16*)(w + (1u << 20));
    _Float16* Em = Eh + (size_t)KCODES * DIM;

    // X planes exactly fill the quant region (64 MiB), rewritten later by assign_k
    _Float16* Xh = (_Float16*)out;
    _Float16* Xm = Xh + (size_t)N_ROWS * DIM;

    binit_k<<<N_ROWS / 256, 256, 0, stream>>>(best);
    cvt_k<<<(N_ROWS * DIM / 8) / 256, 256, 0, stream>>>(x, Xh, Xm, N_ROWS * DIM / 8);
    cvt_k<<<(KCODES * DIM / 8) / 256, 256, 0, stream>>>(embed, Eh, Em, KCODES * DIM / 8);
    norms_k<<<(KCODES * 64) / 256, 256, 0, stream>>>(embed, norm2);
    dist_k<<<(N_ROWS / BM) * (KCODES / BN), 256, 0, stream>>>(Xh, Xm, Eh, Em, norm2, best);
    init2_k<<<2048, 256, 0, stream>>>(cs, eavg, out);
    assign_k<<<N_ROWS, 64, 0, stream>>>(x, embed, best, out);
    sum_k<<<1, 256, 0, stream>>>(out, Ssum);
    inv_k<<<KCODES / 256, 256, 0, stream>>>(out, Ssum, inv_cs);
    normout_k<<<(KCODES * DIM / 4) / 256, 256, 0, stream>>>(out, inv_cs);
}